// Round 7
// baseline (352.657 us; speedup 1.0000x reference)
//
#include <hip/hip_runtime.h>

#define HSZ 50        // real hidden units
#define TSZ 512       // timesteps
#define NB  16        // batch tile per workgroup (MFMA n)
#define UPAD 64       // padded units (MFMA m: 4 tiles)
#define KPAD 72       // hlds u-stride in f16 (16B-aligned rows, conflict-tame)
#define GST  68       // glds u-stride in f32 dwords (16B-aligned, bank-offset 4)

typedef _Float16 half8   __attribute__((ext_vector_type(8)));
typedef _Float16 half2_t __attribute__((ext_vector_type(2)));
typedef float    floatx4 __attribute__((ext_vector_type(4)));
typedef float    floatx2 __attribute__((ext_vector_type(2)));

// sigmoid/tanh via exp+rcp, robust at extremes (proven R4-R6, absmax 9.8e-4)
__device__ __forceinline__ float fast_sig(float x) {
    return __builtin_amdgcn_rcpf(1.0f + __expf(-x));
}
__device__ __forceinline__ float fast_tanh(float x) {
    return fmaf(-2.0f, __builtin_amdgcn_rcpf(1.0f + __expf(2.0f * x)), 1.0f);
}

// Workgroup = 8 waves (512 thr) = one 16-batch stream. C-tiles (4 m-tiles x
// 4 gates) split as (m = w&3, gate-pair = w>>2): 4 MFMAs/wave/step, no k-split.
// Gate pre-activations go to an LDS plane buffer glds[gate][batch][unit];
// activations are re-partitioned 2 unit-batch pairs per THREAD (20 trans vs
// R6's 40 per wave), each thread owning its 2 cell states. h returns via the
// proven f16 h^T double buffer (B-fragment k-contiguous layout). 2 barriers
// per step. Padded units (50..63) have zero weights/bias -> h stays 0.
__global__ __launch_bounds__(512)
void lstm_mfma8(const float* __restrict__ x,
                const float* __restrict__ W_ih,
                const float* __restrict__ W_hh,
                const float* __restrict__ b_ih,
                const float* __restrict__ b_hh,
                const float* __restrict__ W_lin,
                const float* __restrict__ b_lin,
                float* __restrict__ out)
{
    __shared__ float xs[TSZ][NB];                        // x transposed [t][n]
    __shared__ __align__(16) float glds[4][NB][GST];     // gate preacts [g][n][u]
    __shared__ __align__(16) _Float16 hlds[2][NB][KPAD]; // h^T double buffer

    const int tid = threadIdx.x;
    const int w   = tid >> 6;        // wave id 0..7
    const int ln  = tid & 63;        // lane
    const int n   = ln & 15;         // batch column (C col / B col / x col)
    const int q   = ln >> 4;         // quad 0..3
    const int m   = w & 3;           // m-tile (units m*16 .. m*16+15)
    const int g0  = (w >> 2) * 2;    // this wave's gate pair: {0,1} or {2,3}

    // --- stage x transposed: global [b][t] -> LDS [t][b] ---
    const float* xg = x + (size_t)blockIdx.x * NB * TSZ;
    for (int i = tid; i < NB * TSZ; i += 512)
        xs[i & (TSZ - 1)][i >> 9] = xg[i];
    // --- zero h buffers (h0 = 0; k>=50 pad stays 0 forever) ---
    for (int i = tid; i < 2 * NB * KPAD; i += 512)
        ((_Float16*)hlds)[i] = (_Float16)0.0f;

    // --- A fragments: lane holds A[mrow = m*16 + n][k = kt*32 + q*8 + j] ---
    const int uA = m * 16 + n;
    half8 af[2][2];
#pragma unroll
    for (int gi = 0; gi < 2; ++gi) {
#pragma unroll
        for (int kt = 0; kt < 2; ++kt) {
#pragma unroll
            for (int j = 0; j < 8; ++j) {
                const int k = kt * 32 + q * 8 + j;
                const float v = (uA < HSZ && k < HSZ)
                              ? W_hh[((g0 + gi) * HSZ + uA) * HSZ + k] : 0.0f;
                af[gi][kt][j] = (_Float16)v;
            }
        }
    }
    // --- bias / W_ih for this lane's C rows (units ub..ub+3, gates g0,g0+1) ---
    const int ub = m * 16 + q * 4;
    float biasr[2][4], wihr[2][4];
#pragma unroll
    for (int gi = 0; gi < 2; ++gi) {
#pragma unroll
        for (int r = 0; r < 4; ++r) {
            const int u   = ub + r;
            const int row = (g0 + gi) * HSZ + u;
            const bool ok = (u < HSZ);
            biasr[gi][r] = ok ? (b_ih[row] + b_hh[row]) : 0.0f;
            wihr[gi][r]  = ok ? W_ih[row] : 0.0f;
        }
    }

    // --- activation-role mapping: thread handles pairs (na,u0),(na,u0+1) ---
    const int na = tid >> 5;            // 0..15
    const int u0 = (2 * tid) & 63;      // even unit index
    float c2[2] = {0.0f, 0.0f};         // cell state for the 2 pairs

    __syncthreads();                    // xs + hlds ready

#pragma unroll 2
    for (int t = 0; t < TSZ; ++t) {
        const int rb = t & 1, wb = rb ^ 1;

        // B fragments (same for all waves): hlds[rb][n][k-contiguous]
        const half8 bf0 = *(const half8*)&hlds[rb][n][q * 8];
        const half8 bf1 = *(const half8*)&hlds[rb][n][32 + q * 8];
        const float xv  = xs[t][n];

        floatx4 acc[2];
#pragma unroll
        for (int gi = 0; gi < 2; ++gi)
#pragma unroll
            for (int r = 0; r < 4; ++r)
                acc[gi][r] = fmaf(xv, wihr[gi][r], biasr[gi][r]);
#pragma unroll
        for (int gi = 0; gi < 2; ++gi) {
            acc[gi] = __builtin_amdgcn_mfma_f32_16x16x32_f16(af[gi][0], bf0, acc[gi], 0, 0, 0);
            acc[gi] = __builtin_amdgcn_mfma_f32_16x16x32_f16(af[gi][1], bf1, acc[gi], 0, 0, 0);
        }
        // C rows ub..ub+3 are contiguous dwords -> one b128 store per gate.
        *(floatx4*)&glds[g0    ][n][ub] = acc[0];
        *(floatx4*)&glds[g0 + 1][n][ub] = acc[1];
        __syncthreads();                 // gate tiles visible

        // --- activations: 2 unit-batch pairs per thread, lane-local state ---
        const floatx2 vi = *(const floatx2*)&glds[0][na][u0];
        const floatx2 vf = *(const floatx2*)&glds[1][na][u0];
        const floatx2 vg = *(const floatx2*)&glds[2][na][u0];
        const floatx2 vo = *(const floatx2*)&glds[3][na][u0];
        float h01[2];
#pragma unroll
        for (int p = 0; p < 2; ++p) {
            const float si = fast_sig (vi[p]);
            const float sf = fast_sig (vf[p]);
            const float sg = fast_tanh(vg[p]);
            const float so = fast_sig (vo[p]);
            c2[p]  = fmaf(sf, c2[p], si * sg);
            h01[p] = so * fast_tanh(c2[p]);
        }
        *(half2_t*)&hlds[wb][na][u0] = half2_t{(_Float16)h01[0], (_Float16)h01[1]};
        __syncthreads();                 // h(t) visible for next step's B-read
    }

    // --- epilogue: out[n] = b_lin + sum_u h_T[u]*W_lin[u]. TSZ even -> buf 0.
    if (w == 0 && ln < NB) {
        float acc = b_lin[0];
        for (int u = 0; u < HSZ; ++u)
            acc = fmaf((float)hlds[0][ln][u], W_lin[u], acc);
        out[(size_t)blockIdx.x * NB + ln] = acc;
    }
}

extern "C" void kernel_launch(void* const* d_in, const int* in_sizes, int n_in,
                              void* d_out, int out_size, void* d_ws, size_t ws_size,
                              hipStream_t stream) {
    const float* x     = (const float*)d_in[0];
    const float* W_ih  = (const float*)d_in[1];
    const float* W_hh  = (const float*)d_in[2];
    const float* b_ih  = (const float*)d_in[3];
    const float* b_hh  = (const float*)d_in[4];
    const float* W_lin = (const float*)d_in[5];
    const float* b_lin = (const float*)d_in[6];
    float* outp = (float*)d_out;

    const int B = in_sizes[0] / TSZ;   // 2048 -> 128 workgroups of 16 batches
    hipLaunchKernelGGL(lstm_mfma8, dim3(B / NB), dim3(512), 0, stream,
                       x, W_ih, W_hh, b_ih, b_hh, W_lin, b_lin, outp);
}